// Round 9
// baseline (629.812 us; speedup 1.0000x reference)
//
#include <hip/hip_runtime.h>
#include <hip/hip_fp16.h>

// ---------------------------------------------------------------------------
// Bidirectional 5-layer LSTM decoder, B=1024, H=32, T=200, feedback y->x.
// Round 23 = r22 with the cvt_pkrtz type fixed (builtin returns __fp16
// ext_vector(2); bit_cast via that exact type). Content identical to r22:
//   - h-pack via v_cvt_pkrtz_f16_f32 (1 op) instead of 2x cvt + or/shl.
//   - tanh clamp via v_med3_f32 (1 op) instead of fmin+fmax.
//   - sigm via exp2(x * -1/ln2): negate folded into the constant mul.
//   - L0-recurrent MFMA rebalanced: nbh0 (region[p][0], valid post-B1) read
//     in S1, its MFMAs issued in S2, result carried to next-ts SEG0.
// Lessons embedded: r15 (occupancy can't help: wall = per-block serial
// chain), r18 (s_barrier < polls), r20 (chain instrs pay 3-6x issue cost),
// r21 (vmcnt drain was minor).
// Race audit identical to r19-r21.
// ---------------------------------------------------------------------------

#define T_STEPS 200
#define BATCH 1024

#define BIAS_OFF_B  231424            // 1280 floats [l*2+d][u][g]
#define BLIN_OFF_B  236544            // 3 floats
#define START_OFF_B 236556            // 3 floats

typedef _Float16 half8 __attribute__((ext_vector_type(8)));
typedef __fp16 fp16x2 __attribute__((ext_vector_type(2)));
typedef float f32x4 __attribute__((ext_vector_type(4)));
typedef unsigned u32x4 __attribute__((ext_vector_type(4)));

__global__ __launch_bounds__(256) void prep_kernel(
    const float* __restrict__ Wih0, const float* __restrict__ Whh0,
    const float* __restrict__ bih0, const float* __restrict__ bhh0,
    const float* __restrict__ Wih,  const float* __restrict__ Whh,
    const float* __restrict__ bih,  const float* __restrict__ bhh,
    const float* __restrict__ Wlin, const float* __restrict__ blin,
    const float* __restrict__ stok, char* __restrict__ ws)
{
    int i = blockIdx.x * 256 + threadIdx.x;
    _Float16* Wo = (_Float16*)ws;
    float* biasf  = (float*)(ws + BIAS_OFF_B);
    float* blinf  = (float*)(ws + BLIN_OFF_B);
    float* startf = (float*)(ws + START_OFF_B);

    if (i < 16384) {                       // layer-0 A-frags
        int fid = i >> 9, r = i & 511;
        int lane = r >> 3, j = r & 7, q = lane >> 4, m = lane & 15;
        int kk = fid & 1, t = (fid >> 1) & 3, half = (fid >> 3) & 1, d = fid >> 4;
        int k = kk * 32 + q * 8 + j;
        int unit = half * 16 + (m >> 2) * 4 + t;   // q-major, t-minor
        int gr = (m & 3) * 32 + unit;      // torch gate order i,f,g,o
        float v = 0.f;
        if (k < 3)       v = Wih0[(d * 128 + gr) * 3 + k];
        else if (k >= 32) v = Whh0[(d * 128 + gr) * 32 + (k - 32)];
        Wo[i] = (_Float16)v;
    } else if (i < 114688) {               // layers 1-4 A-frags
        int e = i - 16384;
        int fid = e >> 9, r = e & 511;
        int lane = r >> 3, j = r & 7, q = lane >> 4, m = lane & 15;
        int kk = fid % 3, t = (fid / 3) & 3, half = (fid / 12) & 1;
        int d = (fid / 24) & 1, l1 = fid / 48;
        int k = kk * 32 + q * 8 + j;
        int unit = half * 16 + (m >> 2) * 4 + t;   // q-major, t-minor
        int gr = (m & 3) * 32 + unit;
        float v;
        if (k < 64) v = Wih[((l1 * 2 + d) * 128 + gr) * 64 + k];
        else        v = Whh[((l1 * 2 + d) * 128 + gr) * 32 + (k - 64)];
        Wo[i] = (_Float16)v;
    } else if (i < 115712) {               // Wlin A-frags, rows REPLICATED %4
        int e = i - 114688;
        int fid = e >> 9, r = e & 511;
        int lane = r >> 3, j = r & 7, q = lane >> 4, m = lane & 15;
        int k = fid * 32 + q * 8 + j;
        int mr = m & 3;                    // row m holds Wlin[m&3] (row3 = 0)
        Wo[i] = (_Float16)((mr < 3) ? Wlin[mr * 64 + k] : 0.f);
    } else if (i < 115712 + 1280) {        // fused biases [l*2+d][u][g]
        int b = i - 115712;
        int ld = b / 128, rem = b % 128;
        int u = rem / 4, g = rem % 4;
        int gr = g * 32 + u;
        float v;
        if (ld < 2) v = bih0[ld * 128 + gr] + bhh0[ld * 128 + gr];
        else        v = bih[(ld - 2) * 128 + gr] + bhh[(ld - 2) * 128 + gr];
        biasf[b] = v;
    } else if (i < 115712 + 1280 + 3) {
        blinf[i - (115712 + 1280)] = blin[i - (115712 + 1280)];
    } else if (i < 115712 + 1280 + 6) {
        startf[i - (115712 + 1280 + 3)] = stok[i - (115712 + 1280 + 3)];
    }
}

// fast sigmoid: exp2 with folded -1/ln2 + raw v_rcp_f32
__device__ __forceinline__ float sigm(float x) {
    return __builtin_amdgcn_rcpf(1.f + __builtin_amdgcn_exp2f(x * -1.442695041f));
}
// tanh via Pade(7,6), clamp by v_med3 (abs err <= ~7e-4)
__device__ __forceinline__ float tanhx(float x) {
    float xc = __builtin_amdgcn_fmed3f(x, -4.0f, 4.0f);
    float u  = xc * xc;
    float p  = __builtin_fmaf(__builtin_fmaf(u + 378.0f, u, 17325.0f), u, 135135.0f);
    float qd = __builtin_fmaf(__builtin_fmaf(__builtin_fmaf(u, 28.0f, 3150.0f), u, 62370.0f), u, 135135.0f);
    return xc * p * __builtin_amdgcn_rcpf(qd);
}
// one-instruction f32 pair -> packed f16x2 (RTZ; <=1ulp f16 vs RNE)
__device__ __forceinline__ unsigned pk2h(float a, float b) {
    fp16x2 r = __builtin_amdgcn_cvt_pkrtz(a, b);
    return __builtin_bit_cast(unsigned, r);
}

// Park a 16B fragment into a contiguous AGPR quad (r17-proven).
__device__ __forceinline__ half8 park_frag(uint4 v) {
    u32x4 t; t[0] = v.x; t[1] = v.y; t[2] = v.z; t[3] = v.w;
    u32x4 r;
    __asm__("" : "=a"(r) : "0"(t));
    return __builtin_bit_cast(half8, r);
}

// RAW LDS-only barrier (r21-proven): drains lgkm (ds ops) but NOT vmcnt.
__device__ __forceinline__ void bar_lds() {
    __asm__ volatile("s_waitcnt lgkmcnt(0)" ::: "memory");
    __builtin_amdgcn_sched_barrier(0);
    __builtin_amdgcn_s_barrier();
    __builtin_amdgcn_sched_barrier(0);
    __asm__ volatile("" ::: "memory");
}

#define MFMA(A, B, C) __builtin_amdgcn_mfma_f32_16x16x32_f16((A), (B), (C), 0, 0, 0)

// per-wave frag slots (28 frags = 112 AGPR)
#define SL0R(tt)       (tt)                                     // 0..1  (Whh0)
#define SL(l, tt, kk)  (2 + (((l) - 1) * 2 + (tt)) * 3 + (kk))  // 2..25
#define SWL(kk)        (26 + (kk))                              // 26,27

__global__ __launch_bounds__(512, 2) void lstm_kernel(
    const char* __restrict__ ws,
    const float* __restrict__ h0,
    const float* __restrict__ c0,
    const float* __restrict__ Wih0g,
    float* __restrict__ out)
{
    const int tid  = threadIdx.x;
    const int w    = tid >> 6;
    const int d    = w & 1;           // direction
    const int half = (w >> 1) & 1;    // unit half
    const int tp   = w >> 2;          // t-pair (t = 2*tp + tt)
    const int lane = tid & 63;
    const int q    = lane >> 4;       // quad
    const int n    = lane & 15;       // batch row within block
    const int row  = blockIdx.x * 16 + n;

    // parity-doubled regions: [2][5][16 rows][36 words]
    __shared__ unsigned zb[5760];

    const uint4* gw4 = (const uint4*)ws;
    const float* biasf  = (const float*)(ws + BIAS_OFF_B);
    const float* blinf  = (const float*)(ws + BLIN_OFF_B);
    const float* startf = (const float*)(ws + START_OFF_B);

    for (int i = tid; i < 5760; i += 512) zb[i] = 0;
    __syncthreads();

    // ---- park this wave's A-fragments in AGPRs (28 frags = 112 AGPR) ----
    half8 afr[28];
#pragma unroll
    for (int tt = 0; tt < 2; tt++) {      // L0: only the Whh0 (kk=1) frag
        int t = 2 * tp + tt;
        uint4 v = gw4[((((d * 2 + half) * 4 + t) * 2) + 1) * 64 + lane];
        afr[SL0R(tt)] = park_frag(v);
    }
#pragma unroll
    for (int l1 = 0; l1 < 4; l1++)
#pragma unroll
        for (int tt = 0; tt < 2; tt++)
#pragma unroll
            for (int kk = 0; kk < 3; kk++) {
                int t = 2 * tp + tt;
                int fid = (((l1 * 2 + d) * 2 + half) * 4 + t) * 3 + kk;
                uint4 v = gw4[2048 + fid * 64 + lane];
                afr[SL(l1 + 1, tt, kk)] = park_frag(v);
            }
#pragma unroll
    for (int kk = 0; kk < 2; kk++) {
        uint4 v = gw4[14336 + kk * 64 + lane];
        afr[SWL(kk)] = park_frag(v);
    }

    // ---- L0 input-weight columns (K=3) in registers: Wc[tt][g*3+k] ------
    float WcA[12], WcB[12];
    {
        int uA = half * 16 + q * 4 + 2 * tp;
#pragma unroll
        for (int g = 0; g < 4; g++)
#pragma unroll
            for (int k = 0; k < 3; k++) {
                WcA[g * 3 + k] = Wih0g[(d * 128 + g * 32 + uA) * 3 + k];
                WcB[g * 3 + k] = Wih0g[(d * 128 + g * 32 + uA + 1) * 3 + k];
            }
    }

    // ---- biases (VGPRs), c-state, h-init into PARITY-1 regions ----------
    f32x4 bias[5][2];
    float cs[5][2];
    {
        unsigned short* zh1 = (unsigned short*)(zb + 2880);   // parity 1
#pragma unroll
        for (int l = 0; l < 5; l++)
#pragma unroll
            for (int tt = 0; tt < 2; tt++) {
                int unit = half * 16 + q * 4 + (2 * tp + tt); // q-major remap
                bias[l][tt] = *(const f32x4*)(biasf + ((l * 2 + d) * 32 + unit) * 4);
                int idx = ((2 * l + d) * BATCH + row) * 32 + unit;
                cs[l][tt] = c0[idx];
                zh1[l * 1152 + n * 72 + d * 32 + unit] = __builtin_bit_cast(unsigned short, (_Float16)h0[idx]);
            }
    }
    const float bl0 = blinf[0], bl1 = blinf[1], bl2 = blinf[2];
    float y0 = startf[0], y1 = startf[1], y2 = startf[2];
    __syncthreads();

#define LOADAT(BASE, L, DD) \
    __builtin_bit_cast(half8, *(const uint4*)&(BASE)[(L) * 576 + n * 36 + (DD) * 16 + q * 4])
#define STPACK(ZH, L, P) \
    *(unsigned*)((ZH) + (L) * 1152 + n * 72 + d * 32 + half * 16 + q * 4 + 2 * tp) = (P);
#define ACT_STORE(ZH, L, A0, A1, CSL)                                   \
    {                                                                    \
        f32x4 a2[2] = {(A0), (A1)};                                      \
        float hv[2];                                                     \
        _Pragma("unroll")                                                \
        for (int tt = 0; tt < 2; tt++) {                                 \
            float ii = sigm(a2[tt][0]), ff = sigm(a2[tt][1]);            \
            float gg = tanhx(a2[tt][2]), oo = sigm(a2[tt][3]);           \
            (CSL)[tt] = ff * (CSL)[tt] + ii * gg;                        \
            hv[tt] = oo * tanhx((CSL)[tt]);                              \
        }                                                                \
        STPACK(ZH, L, pk2h(hv[0], hv[1]));                               \
    }

    const f32x4 fz = (f32x4){0.f, 0.f, 0.f, 0.f};

    // accn pipeline: next-layer recurrent MFMA result, crosses barriers
    f32x4 accnA, accnB;
    {
        half8 bh0i = LOADAT(zb + 2880, 0, d);     // parity-1 region 0 = h(-1)
        accnA = MFMA(afr[SL0R(0)], bh0i, bias[0][0]);
        accnB = MFMA(afr[SL0R(1)], bh0i, bias[0][1]);
    }
    // L0-recurrent pipeline for ts+1 (computed mid-ts from region[p][0])
    half8 nbh0 = (half8)(_Float16)0.f;
    f32x4 accLA = fz, accLB = fz;

    for (int ts = 0; ts < T_STEPS; ts++) {
        const int p = ts & 1;
        unsigned* zbp = zb + p * 2880;            // current-parity regions
        unsigned* zbq = zb + (p ^ 1) * 2880;      // previous-parity regions
        unsigned short* zhp = (unsigned short*)zbp;

        // ---------- SEG0: layer 0 (no pre-barrier; y + accn in regs) -----
        {
            half8 nb2 = LOADAT(zbq, 1, d);        // h1(ts-1): prefetch early
            f32x4 acc0 = accnA, acc1 = accnB;
#pragma unroll
            for (int g = 0; g < 4; g++) {         // W_ih0 (K=3) on the VALU
                acc0[g] = __builtin_fmaf(WcA[g * 3 + 0], y0,
                          __builtin_fmaf(WcA[g * 3 + 1], y1,
                          __builtin_fmaf(WcA[g * 3 + 2], y2, acc0[g])));
                acc1[g] = __builtin_fmaf(WcB[g * 3 + 0], y0,
                          __builtin_fmaf(WcB[g * 3 + 1], y1,
                          __builtin_fmaf(WcB[g * 3 + 2], y2, acc1[g])));
            }
            accnA = MFMA(afr[SL(1, 0, 2)], nb2, bias[1][0]);   // L1 recurrent
            accnB = MFMA(afr[SL(1, 1, 2)], nb2, bias[1][1]);
            ACT_STORE(zhp, 0, acc0, acc1, cs[0]);
            bar_lds();                                         // B1
        }

        // ---------- SEG 1..3 (split-K: parallel MFMAs, add at end) -------
#pragma unroll
        for (int l = 1; l <= 3; l++) {
            half8 b0 = LOADAT(zbp, l - 1, 0);
            half8 b1 = LOADAT(zbp, l - 1, 1);
            half8 nb2 = LOADAT(zbq, l + 1, d);    // h_{l+1}(ts-1)
            if (l == 1) nbh0 = LOADAT(zbp, 0, d); // h0(ts): valid post-B1
            f32x4 acc0 = MFMA(afr[SL(l, 0, 0)], b0, accnA);
            f32x4 acc0b = MFMA(afr[SL(l, 0, 1)], b1, fz);
            f32x4 acc1 = MFMA(afr[SL(l, 1, 0)], b0, accnB);
            f32x4 acc1b = MFMA(afr[SL(l, 1, 1)], b1, fz);
            accnA = MFMA(afr[SL(l + 1, 0, 2)], nb2, bias[l + 1][0]);
            accnB = MFMA(afr[SL(l + 1, 1, 2)], nb2, bias[l + 1][1]);
            if (l == 2) {                          // L0 recurrent for ts+1
                accLA = MFMA(afr[SL0R(0)], nbh0, bias[0][0]);
                accLB = MFMA(afr[SL0R(1)], nbh0, bias[0][1]);
            }
            acc0 += acc0b;
            acc1 += acc1b;
            ACT_STORE(zhp, l, acc0, acc1, cs[l]);
            bar_lds();                                         // B2..B4
        }

        // ---------- SEG4 (no accn MFMAs: rebalanced to S2) ---------------
        {
            half8 b0 = LOADAT(zbp, 3, 0);
            half8 b1 = LOADAT(zbp, 3, 1);
            f32x4 acc0 = MFMA(afr[SL(4, 0, 0)], b0, accnA);
            f32x4 acc0b = MFMA(afr[SL(4, 0, 1)], b1, fz);
            f32x4 acc1 = MFMA(afr[SL(4, 1, 0)], b0, accnB);
            f32x4 acc1b = MFMA(afr[SL(4, 1, 1)], b1, fz);
            acc0 += acc0b;
            acc1 += acc1b;
            ACT_STORE(zhp, 4, acc0, acc1, cs[4]);
            accnA = accLA;                         // L0 rec result for ts+1
            accnB = accLB;
            bar_lds();                                         // B5
        }

        // ---------- Y: all waves; replicated Wlin -> y on ALL lanes ------
        {
            half8 c0f = LOADAT(zbp, 4, 0);
            half8 c1f = LOADAT(zbp, 4, 1);
            f32x4 acc  = MFMA(afr[SWL(0)], c0f, fz);
            f32x4 accb = MFMA(afr[SWL(1)], c1f, fz);
            y0 = tanhx(acc[0] + accb[0] + bl0);   // valid on every lane
            y1 = tanhx(acc[1] + accb[1] + bl1);
            y2 = tanhx(acc[2] + accb[2] + bl2);
            if (w == 0 && q == 0) {
                float* op = out + (ts * BATCH + row) * 3;
                op[0] = y0; op[1] = y1; op[2] = y2;   // fire-and-forget
            }
        }
        // no barrier: Y reads region[p][4]; next write to it is SEG4@(ts+2).
    }
#undef LOADAT
#undef STPACK
#undef ACT_STORE
}

extern "C" void kernel_launch(void* const* d_in, const int* in_sizes, int n_in,
                              void* d_out, int out_size, void* d_ws, size_t ws_size,
                              hipStream_t stream)
{
    const float* h0   = (const float*)d_in[0];
    const float* c0   = (const float*)d_in[1];
    const float* stok = (const float*)d_in[2];
    const float* Wih0 = (const float*)d_in[3];
    const float* Whh0 = (const float*)d_in[4];
    const float* bih0 = (const float*)d_in[5];
    const float* bhh0 = (const float*)d_in[6];
    const float* Wih  = (const float*)d_in[7];
    const float* Whh  = (const float*)d_in[8];
    const float* bih  = (const float*)d_in[9];
    const float* bhh  = (const float*)d_in[10];
    const float* Wlin = (const float*)d_in[11];
    const float* blin = (const float*)d_in[12];

    prep_kernel<<<458, 256, 0, stream>>>(Wih0, Whh0, bih0, bhh0, Wih, Whh,
                                         bih, bhh, Wlin, blin, stok, (char*)d_ws);
    lstm_kernel<<<64, 512, 0, stream>>>((const char*)d_ws, h0, c0, Wih0,
                                        (float*)d_out);
}